// Round 1
// baseline (2787.972 us; speedup 1.0000x reference)
//
#include <hip/hip_runtime.h>
#include <math.h>

#define GPB 4  // g's per block in fused kernel

// ---------------------------------------------------------------------------
// Phase 1: edge scatter.  agg[r][l*128+d] += v * x[l][c][d]
// One wave (64 lanes) per edge; lane handles 4 consecutive d's via float4.
// ---------------------------------------------------------------------------
__global__ __launch_bounds__(256) void scatter_kernel(
    const float* __restrict__ x, const int* __restrict__ rows,
    const int* __restrict__ cols, const float* __restrict__ vals,
    float* __restrict__ agg, int E, int GD) {
  int e = blockIdx.x * 4 + (threadIdx.x >> 6);
  if (e >= E) return;
  int lane = threadIdx.x & 63;
  int r = rows[e];
  int c = cols[e];
  float v = vals[e];
  int l = lane >> 5;           // 0 or 1
  int d4 = (lane & 31) << 2;   // 0,4,...,124

  const float4 xv = *reinterpret_cast<const float4*>(
      x + (size_t)l * GD + (size_t)c * 128 + d4);
  float* dst = agg + (size_t)r * 256 + l * 128 + d4;
  atomicAdd(dst + 0, v * xv.x);
  atomicAdd(dst + 1, v * xv.y);
  atomicAdd(dst + 2, v * xv.z);
  atomicAdd(dst + 3, v * xv.w);
}

// ---------------------------------------------------------------------------
// Phase 2: fused  h = y @ W^T + b ; s = SiLU(h) ; out = LayerNorm(s)*gamma+beta
// Block = 128 threads (thread o = output channel), GPB g's per block.
// y rows staged in LDS (all-lane broadcast reads), W rows via L1/L2.
// ---------------------------------------------------------------------------
__global__ __launch_bounds__(128) void fused_kernel(
    const float* __restrict__ agg, const float* __restrict__ W,
    const float* __restrict__ b, const float* __restrict__ gamma,
    const float* __restrict__ beta, float* __restrict__ out, int G) {
  __shared__ float y[GPB * 256];
  __shared__ float part[2][GPB * 2][2];  // [wave][(gi,l)][sum|sumsq]

  const int tid = threadIdx.x;
  const int g0 = blockIdx.x * GPB;

  // cooperative load of GPB*256 = 1024 floats (coalesced float4)
  {
    const float4* src = reinterpret_cast<const float4*>(agg + (size_t)g0 * 256);
    float4* dst = reinterpret_cast<float4*>(y);
    dst[tid] = src[tid];
    dst[tid + 128] = src[tid + 128];
  }
  __syncthreads();

  const int o = tid;
  float acc[GPB][2];
#pragma unroll
  for (int gi = 0; gi < GPB; ++gi) {
    acc[gi][0] = 0.f;
    acc[gi][1] = 0.f;
  }

  const float4* wrow = reinterpret_cast<const float4*>(W + (size_t)o * 128);
#pragma unroll 8
  for (int d4 = 0; d4 < 32; ++d4) {
    const float4 w = wrow[d4];
#pragma unroll
    for (int gi = 0; gi < GPB; ++gi) {
#pragma unroll
      for (int l = 0; l < 2; ++l) {
        const float4 yv =
            *reinterpret_cast<const float4*>(&y[gi * 256 + l * 128 + d4 * 4]);
        acc[gi][l] += w.x * yv.x + w.y * yv.y + w.z * yv.z + w.w * yv.w;
      }
    }
  }

  const float bias = b[o];
  float sv[GPB][2];
#pragma unroll
  for (int gi = 0; gi < GPB; ++gi) {
#pragma unroll
    for (int l = 0; l < 2; ++l) {
      float h = acc[gi][l] + bias;
      sv[gi][l] = h / (1.0f + expf(-h));  // SiLU
    }
  }

  // LN reductions: per (gi,l) row, sum & sumsq over the 128 o's.
  const int wave = tid >> 6;
#pragma unroll
  for (int gi = 0; gi < GPB; ++gi) {
#pragma unroll
    for (int l = 0; l < 2; ++l) {
      float s = sv[gi][l];
      float sum = s, sq = s * s;
#pragma unroll
      for (int m = 32; m > 0; m >>= 1) {
        sum += __shfl_xor(sum, m);
        sq += __shfl_xor(sq, m);
      }
      if ((tid & 63) == 0) {
        part[wave][gi * 2 + l][0] = sum;
        part[wave][gi * 2 + l][1] = sq;
      }
    }
  }
  __syncthreads();

  const float gam = gamma[o];
  const float bet = beta[o];
#pragma unroll
  for (int gi = 0; gi < GPB; ++gi) {
#pragma unroll
    for (int l = 0; l < 2; ++l) {
      float sum = part[0][gi * 2 + l][0] + part[1][gi * 2 + l][0];
      float sq = part[0][gi * 2 + l][1] + part[1][gi * 2 + l][1];
      float mu = sum * (1.0f / 128.0f);
      float var = sq * (1.0f / 128.0f) - mu * mu;
      float inv = 1.0f / sqrtf(var + 1e-5f);
      out[(size_t)l * G * 128 + (size_t)(g0 + gi) * 128 + o] =
          (sv[gi][l] - mu) * inv * gam + bet;
    }
  }
}

// ---------------------------------------------------------------------------
extern "C" void kernel_launch(void* const* d_in, const int* in_sizes, int n_in,
                              void* d_out, int out_size, void* d_ws,
                              size_t ws_size, hipStream_t stream) {
  const float* x = (const float*)d_in[0];
  const int* rows = (const int*)d_in[1];
  const int* cols = (const int*)d_in[2];
  const float* vals = (const float*)d_in[3];
  const float* W = (const float*)d_in[4];
  const float* b = (const float*)d_in[5];
  const float* gamma = (const float*)d_in[6];
  const float* beta = (const float*)d_in[7];

  const int E = in_sizes[1];
  const int G = in_sizes[0] / 256;  // L=2, D=128
  const int GD = G * 128;

  float* agg = (float*)d_ws;  // [G][256]
  hipMemsetAsync(d_ws, 0, (size_t)G * 256 * sizeof(float), stream);

  scatter_kernel<<<(E + 3) / 4, 256, 0, stream>>>(x, rows, cols, vals, agg, E,
                                                  GD);
  fused_kernel<<<(G + GPB - 1) / GPB, 128, 0, stream>>>(agg, W, b, gamma, beta,
                                                        (float*)d_out, G);
}

// Round 2
// 433.681 us; speedup vs baseline: 6.4286x; 6.4286x over previous
//
#include <hip/hip_runtime.h>
#include <math.h>

#define GPB 4  // g's per block in fused kernel

// ---------------------------------------------------------------------------
// CSR build: histogram -> scan -> scatter-build (counting sort by row)
// ---------------------------------------------------------------------------
__global__ __launch_bounds__(256) void hist_kernel(const int* __restrict__ rows,
                                                   int* __restrict__ counts,
                                                   int E) {
  int e = blockIdx.x * 256 + threadIdx.x;
  if (e < E) atomicAdd(&counts[rows[e]], 1);
}

// Single-block exclusive scan over G counts; also writes offsets[G]=E and
// initializes the cursor array (atomic allocation pointers) = offsets.
__global__ __launch_bounds__(1024) void scan_kernel(
    const int* __restrict__ counts, int* __restrict__ offsets,
    int* __restrict__ cursor, int G) {
  __shared__ int tsum[1024];
  const int tid = threadIdx.x;
  const int chunk = (G + 1023) / 1024;
  const int begin = tid * chunk;
  const int end = min(begin + chunk, G);

  int s = 0;
  for (int i = begin; i < end; ++i) s += counts[i];
  tsum[tid] = s;
  __syncthreads();
  // Hillis-Steele inclusive scan over 1024 thread totals
  for (int off = 1; off < 1024; off <<= 1) {
    int v = (tid >= off) ? tsum[tid - off] : 0;
    __syncthreads();
    tsum[tid] += v;
    __syncthreads();
  }
  int run = tsum[tid] - s;  // exclusive prefix for this thread's chunk
  for (int i = begin; i < end; ++i) {
    offsets[i] = run;
    cursor[i] = run;
    run += counts[i];
  }
  if (tid == 1023) offsets[G] = run;  // == E (last thread's chunk is empty/last)
}

__global__ __launch_bounds__(256) void build_kernel(
    const int* __restrict__ rows, const int* __restrict__ cols,
    const float* __restrict__ vals, int* __restrict__ cursor,
    int* __restrict__ sc, float* __restrict__ sv, int E) {
  int e = blockIdx.x * 256 + threadIdx.x;
  if (e >= E) return;
  int pos = atomicAdd(&cursor[rows[e]], 1);
  sc[pos] = cols[e];
  sv[pos] = vals[e];
}

// ---------------------------------------------------------------------------
// Gather: one wave per row g.  agg[g][l*128+d] = sum_e v_e * x[l][c_e][d]
// Lane -> (l = lane>>5, d4 = (lane&31)*4), float4 accumulation in registers.
// ---------------------------------------------------------------------------
__global__ __launch_bounds__(256) void gather_kernel(
    const float* __restrict__ x, const int* __restrict__ offsets,
    const int* __restrict__ sc, const float* __restrict__ sv,
    float* __restrict__ agg, int G, int GD) {
  int g = blockIdx.x * 4 + (threadIdx.x >> 6);
  if (g >= G) return;
  const int lane = threadIdx.x & 63;
  const int l = lane >> 5;
  const int q = lane & 31;  // float4 index within the 128-float row
  const float4* xs = reinterpret_cast<const float4*>(x + (size_t)l * GD);

  int i = offsets[g];
  const int end = offsets[g + 1];
  float4 acc = make_float4(0.f, 0.f, 0.f, 0.f);

  for (; i + 1 < end; i += 2) {
    int c0 = sc[i], c1 = sc[i + 1];
    float v0 = sv[i], v1 = sv[i + 1];
    float4 a = xs[(size_t)c0 * 32 + q];
    float4 b = xs[(size_t)c1 * 32 + q];
    acc.x += v0 * a.x + v1 * b.x;
    acc.y += v0 * a.y + v1 * b.y;
    acc.z += v0 * a.z + v1 * b.z;
    acc.w += v0 * a.w + v1 * b.w;
  }
  if (i < end) {
    int c0 = sc[i];
    float v0 = sv[i];
    float4 a = xs[(size_t)c0 * 32 + q];
    acc.x += v0 * a.x;
    acc.y += v0 * a.y;
    acc.z += v0 * a.z;
    acc.w += v0 * a.w;
  }
  *reinterpret_cast<float4*>(agg + (size_t)g * 256 + l * 128 + q * 4) = acc;
}

// ---------------------------------------------------------------------------
// Fused  h = y @ W^T + b ; s = SiLU(h) ; out = LayerNorm(s)*gamma+beta
// ---------------------------------------------------------------------------
__global__ __launch_bounds__(128) void fused_kernel(
    const float* __restrict__ agg, const float* __restrict__ W,
    const float* __restrict__ b, const float* __restrict__ gamma,
    const float* __restrict__ beta, float* __restrict__ out, int G) {
  __shared__ float y[GPB * 256];
  __shared__ float part[2][GPB * 2][2];  // [wave][(gi,l)][sum|sumsq]

  const int tid = threadIdx.x;
  const int g0 = blockIdx.x * GPB;

  {
    const float4* src = reinterpret_cast<const float4*>(agg + (size_t)g0 * 256);
    float4* dst = reinterpret_cast<float4*>(y);
    dst[tid] = src[tid];
    dst[tid + 128] = src[tid + 128];
  }
  __syncthreads();

  const int o = tid;
  float acc[GPB][2];
#pragma unroll
  for (int gi = 0; gi < GPB; ++gi) {
    acc[gi][0] = 0.f;
    acc[gi][1] = 0.f;
  }

  const float4* wrow = reinterpret_cast<const float4*>(W + (size_t)o * 128);
#pragma unroll 8
  for (int d4 = 0; d4 < 32; ++d4) {
    const float4 w = wrow[d4];
#pragma unroll
    for (int gi = 0; gi < GPB; ++gi) {
#pragma unroll
      for (int l = 0; l < 2; ++l) {
        const float4 yv =
            *reinterpret_cast<const float4*>(&y[gi * 256 + l * 128 + d4 * 4]);
        acc[gi][l] += w.x * yv.x + w.y * yv.y + w.z * yv.z + w.w * yv.w;
      }
    }
  }

  const float bias = b[o];
  float sv_[GPB][2];
#pragma unroll
  for (int gi = 0; gi < GPB; ++gi) {
#pragma unroll
    for (int l = 0; l < 2; ++l) {
      float h = acc[gi][l] + bias;
      sv_[gi][l] = h / (1.0f + expf(-h));  // SiLU
    }
  }

  const int wave = tid >> 6;
#pragma unroll
  for (int gi = 0; gi < GPB; ++gi) {
#pragma unroll
    for (int l = 0; l < 2; ++l) {
      float s = sv_[gi][l];
      float sum = s, sq = s * s;
#pragma unroll
      for (int m = 32; m > 0; m >>= 1) {
        sum += __shfl_xor(sum, m);
        sq += __shfl_xor(sq, m);
      }
      if ((tid & 63) == 0) {
        part[wave][gi * 2 + l][0] = sum;
        part[wave][gi * 2 + l][1] = sq;
      }
    }
  }
  __syncthreads();

  const float gam = gamma[o];
  const float bet = beta[o];
#pragma unroll
  for (int gi = 0; gi < GPB; ++gi) {
#pragma unroll
    for (int l = 0; l < 2; ++l) {
      float sum = part[0][gi * 2 + l][0] + part[1][gi * 2 + l][0];
      float sq = part[0][gi * 2 + l][1] + part[1][gi * 2 + l][1];
      float mu = sum * (1.0f / 128.0f);
      float var = sq * (1.0f / 128.0f) - mu * mu;
      float inv = 1.0f / sqrtf(var + 1e-5f);
      out[(size_t)l * G * 128 + (size_t)(g0 + gi) * 128 + o] =
          (sv_[gi][l] - mu) * inv * gam + bet;
    }
  }
}

// ---------------------------------------------------------------------------
extern "C" void kernel_launch(void* const* d_in, const int* in_sizes, int n_in,
                              void* d_out, int out_size, void* d_ws,
                              size_t ws_size, hipStream_t stream) {
  const float* x = (const float*)d_in[0];
  const int* rows = (const int*)d_in[1];
  const int* cols = (const int*)d_in[2];
  const float* vals = (const float*)d_in[3];
  const float* W = (const float*)d_in[4];
  const float* b = (const float*)d_in[5];
  const float* gamma = (const float*)d_in[6];
  const float* beta = (const float*)d_in[7];

  const int E = in_sizes[1];
  const int G = in_sizes[0] / 256;  // L=2, D=128
  const int GD = G * 128;

  // workspace layout
  char* ws = (char*)d_ws;
  float* agg = (float*)ws;                              // G*256 f32
  int* counts = (int*)(ws + (size_t)G * 1024);          // G int
  int* offsets = counts + G;                            // G+1 int
  int* cursor = offsets + (G + 1);                      // G int
  int* sc = cursor + G;                                 // E int
  float* svals = (float*)(sc + E);                      // E f32

  hipMemsetAsync(counts, 0, (size_t)G * sizeof(int), stream);
  hist_kernel<<<(E + 255) / 256, 256, 0, stream>>>(rows, counts, E);
  scan_kernel<<<1, 1024, 0, stream>>>(counts, offsets, cursor, G);
  build_kernel<<<(E + 255) / 256, 256, 0, stream>>>(rows, cols, vals, cursor,
                                                    sc, svals, E);
  gather_kernel<<<(G + 3) / 4, 256, 0, stream>>>(x, offsets, sc, svals, agg, G,
                                                 GD);
  fused_kernel<<<(G + GPB - 1) / GPB, 128, 0, stream>>>(agg, W, b, gamma, beta,
                                                        (float*)d_out, G);
}

// Round 3
// 344.971 us; speedup vs baseline: 8.0818x; 1.2572x over previous
//
#include <hip/hip_runtime.h>
#include <hip/hip_bf16.h>
#include <math.h>

typedef short bf16x8 __attribute__((ext_vector_type(8)));
typedef float f32x4 __attribute__((ext_vector_type(4)));

#define SPW 4  // stripes (16 rows each) per wave in the MFMA kernel

// ---------------------------------------------------------------------------
// CSR build: histogram -> scan -> scatter-build (counting sort by row)
// ---------------------------------------------------------------------------
__global__ __launch_bounds__(256) void hist_kernel(const int* __restrict__ rows,
                                                   int* __restrict__ counts,
                                                   int E) {
  int e = blockIdx.x * 256 + threadIdx.x;
  if (e < E) atomicAdd(&counts[rows[e]], 1);
}

__global__ __launch_bounds__(1024) void scan_kernel(
    const int* __restrict__ counts, int* __restrict__ offsets,
    int* __restrict__ cursor, int G) {
  __shared__ int tsum[1024];
  const int tid = threadIdx.x;
  const int chunk = (G + 1023) / 1024;
  const int begin = tid * chunk;
  const int end = min(begin + chunk, G);

  int s = 0;
  for (int i = begin; i < end; ++i) s += counts[i];
  tsum[tid] = s;
  __syncthreads();
  for (int off = 1; off < 1024; off <<= 1) {
    int v = (tid >= off) ? tsum[tid - off] : 0;
    __syncthreads();
    tsum[tid] += v;
    __syncthreads();
  }
  int run = tsum[tid] - s;
  for (int i = begin; i < end; ++i) {
    offsets[i] = run;
    cursor[i] = run;
    run += counts[i];
  }
  if (tid == 1023) offsets[G] = run;
}

__global__ __launch_bounds__(256) void build_kernel(
    const int* __restrict__ rows, const int* __restrict__ cols,
    const float* __restrict__ vals, int* __restrict__ cursor,
    int* __restrict__ sc, float* __restrict__ sv, int E) {
  int e = blockIdx.x * 256 + threadIdx.x;
  if (e >= E) return;
  int pos = atomicAdd(&cursor[rows[e]], 1);
  sc[pos] = cols[e];
  sv[pos] = vals[e];
}

// ---------------------------------------------------------------------------
// W fp32 -> bf16
// ---------------------------------------------------------------------------
__global__ __launch_bounds__(256) void wconv_kernel(const float* __restrict__ W,
                                                    __hip_bfloat16* __restrict__ Wb,
                                                    int n) {
  int i = blockIdx.x * 256 + threadIdx.x;
  if (i < n) Wb[i] = __float2bfloat16(W[i]);
}

// ---------------------------------------------------------------------------
// Gather: one wave per row g; fp32 accumulate, bf16 store.
// aggb row index = g*2 + l, 128 bf16 per row.
// ---------------------------------------------------------------------------
__global__ __launch_bounds__(256) void gather_kernel(
    const float* __restrict__ x, const int* __restrict__ offsets,
    const int* __restrict__ sc, const float* __restrict__ sv,
    __hip_bfloat16* __restrict__ aggb, int G, int GD) {
  int g = blockIdx.x * 4 + (threadIdx.x >> 6);
  if (g >= G) return;
  const int lane = threadIdx.x & 63;
  const int l = lane >> 5;
  const int q = lane & 31;
  const float4* xs = reinterpret_cast<const float4*>(x + (size_t)l * GD);

  int i = offsets[g];
  const int end = offsets[g + 1];
  float4 acc = make_float4(0.f, 0.f, 0.f, 0.f);

  for (; i + 1 < end; i += 2) {
    int c0 = sc[i], c1 = sc[i + 1];
    float v0 = sv[i], v1 = sv[i + 1];
    float4 a = xs[(size_t)c0 * 32 + q];
    float4 b = xs[(size_t)c1 * 32 + q];
    acc.x += v0 * a.x + v1 * b.x;
    acc.y += v0 * a.y + v1 * b.y;
    acc.z += v0 * a.z + v1 * b.z;
    acc.w += v0 * a.w + v1 * b.w;
  }
  if (i < end) {
    int c0 = sc[i];
    float v0 = sv[i];
    float4 a = xs[(size_t)c0 * 32 + q];
    acc.x += v0 * a.x;
    acc.y += v0 * a.y;
    acc.z += v0 * a.z;
    acc.w += v0 * a.w;
  }
  ushort4 st;
  __hip_bfloat16 h;
  h = __float2bfloat16(acc.x); st.x = *reinterpret_cast<ushort*>(&h);
  h = __float2bfloat16(acc.y); st.y = *reinterpret_cast<ushort*>(&h);
  h = __float2bfloat16(acc.z); st.z = *reinterpret_cast<ushort*>(&h);
  h = __float2bfloat16(acc.w); st.w = *reinterpret_cast<ushort*>(&h);
  *reinterpret_cast<ushort4*>(
      reinterpret_cast<ushort*>(aggb) + (size_t)(g * 2 + l) * 128 + q * 4) = st;
}

// ---------------------------------------------------------------------------
// MFMA GEMM + SiLU + LayerNorm.
// One wave = 16-row stripe x 128 outputs; W entirely in registers (B-frags);
// mfma_f32_16x16x32_bf16; D layout: col(o)=lane&15, row=(lane>>4)*4+reg.
// ---------------------------------------------------------------------------
__global__ __launch_bounds__(256) void mfma_fused_kernel(
    const __hip_bfloat16* __restrict__ agg,
    const __hip_bfloat16* __restrict__ Wb, const float* __restrict__ b,
    const float* __restrict__ gamma, const float* __restrict__ beta,
    float* __restrict__ out, int G) {
  const int lane = threadIdx.x & 63;
  const int wid = blockIdx.x * 4 + (threadIdx.x >> 6);
  const int nstripes = (G * 2) >> 4;  // 16 rows per stripe

  const int o_lo = lane & 15;   // o mod 16 (C/D col, B "col")
  const int kg = lane >> 4;     // k-chunk group / row-quad

  // B fragments: full 128x128 W in registers. wf[on][kc] covers
  // o = on*16 + o_lo, k = kc*32 + kg*8 .. +7  (B^T layout, same as A)
  bf16x8 wf[8][4];
  const ushort* wp = reinterpret_cast<const ushort*>(Wb);
#pragma unroll
  for (int on = 0; on < 8; ++on)
#pragma unroll
    for (int kc = 0; kc < 4; ++kc)
      wf[on][kc] = *reinterpret_cast<const bf16x8*>(
          wp + (size_t)(on * 16 + o_lo) * 128 + kc * 32 + kg * 8);

  float bias[8], gam[8], bet[8];
#pragma unroll
  for (int on = 0; on < 8; ++on) {
    bias[on] = b[on * 16 + o_lo];
    gam[on] = gamma[on * 16 + o_lo];
    bet[on] = beta[on * 16 + o_lo];
  }

  const ushort* ap = reinterpret_cast<const ushort*>(agg);

  for (int i = 0; i < SPW; ++i) {
    const int s = wid * SPW + i;
    if (s >= nstripes) return;
    const int row0 = s << 4;

    bf16x8 af[4];
#pragma unroll
    for (int kc = 0; kc < 4; ++kc)
      af[kc] = *reinterpret_cast<const bf16x8*>(
          ap + (size_t)(row0 + o_lo) * 128 + kc * 32 + kg * 8);

    f32x4 acc[8];
#pragma unroll
    for (int on = 0; on < 8; ++on) acc[on] = (f32x4){0.f, 0.f, 0.f, 0.f};

#pragma unroll
    for (int kc = 0; kc < 4; ++kc)
#pragma unroll
      for (int on = 0; on < 8; ++on)
        acc[on] = __builtin_amdgcn_mfma_f32_16x16x32_bf16(af[kc], wf[on][kc],
                                                          acc[on], 0, 0, 0);

    // epilogue: this lane holds rows r = row0 + kg*4 + reg (reg 0..3),
    // o = on*16 + o_lo (on 0..7).  LN over the 16 lanes of each lane-group.
#pragma unroll
    for (int reg = 0; reg < 4; ++reg) {
      const int r = row0 + kg * 4 + reg;
      float svv[8];
      float sum = 0.f, sq = 0.f;
#pragma unroll
      for (int on = 0; on < 8; ++on) {
        float h = acc[on][reg] + bias[on];
        float e = h / (1.f + expf(-h));  // SiLU
        svv[on] = e;
        sum += e;
        sq += e * e;
      }
#pragma unroll
      for (int m = 1; m <= 8; m <<= 1) {
        sum += __shfl_xor(sum, m);
        sq += __shfl_xor(sq, m);
      }
      const float mu = sum * (1.f / 128.f);
      const float var = sq * (1.f / 128.f) - mu * mu;
      const float inv = rsqrtf(var + 1e-5f);
      float* op = out + ((size_t)(r & 1) * G + (r >> 1)) * 128 + o_lo;
#pragma unroll
      for (int on = 0; on < 8; ++on)
        op[on * 16] = (svv[on] - mu) * inv * gam[on] + bet[on];
    }
  }
}

// ---------------------------------------------------------------------------
extern "C" void kernel_launch(void* const* d_in, const int* in_sizes, int n_in,
                              void* d_out, int out_size, void* d_ws,
                              size_t ws_size, hipStream_t stream) {
  const float* x = (const float*)d_in[0];
  const int* rows = (const int*)d_in[1];
  const int* cols = (const int*)d_in[2];
  const float* vals = (const float*)d_in[3];
  const float* W = (const float*)d_in[4];
  const float* b = (const float*)d_in[5];
  const float* gamma = (const float*)d_in[6];
  const float* beta = (const float*)d_in[7];

  const int E = in_sizes[1];
  const int G = in_sizes[0] / 256;  // L=2, D=128
  const int GD = G * 128;

  // workspace layout
  char* ws = (char*)d_ws;
  __hip_bfloat16* aggb = (__hip_bfloat16*)ws;               // 2G*128 bf16
  __hip_bfloat16* Wb = (__hip_bfloat16*)(ws + (size_t)G * 512);  // 16384 bf16
  int* counts = (int*)(ws + (size_t)G * 512 + 32768);       // G
  int* offsets = counts + G;                                // G+1
  int* cursor = offsets + (G + 1);                          // G
  int* sc = cursor + G;                                     // E
  float* svals = (float*)(sc + E);                          // E

  hipMemsetAsync(counts, 0, (size_t)G * sizeof(int), stream);
  wconv_kernel<<<64, 256, 0, stream>>>(W, Wb, 128 * 128);
  hist_kernel<<<(E + 255) / 256, 256, 0, stream>>>(rows, counts, E);
  scan_kernel<<<1, 1024, 0, stream>>>(counts, offsets, cursor, G);
  build_kernel<<<(E + 255) / 256, 256, 0, stream>>>(rows, cols, vals, cursor,
                                                    sc, svals, E);
  gather_kernel<<<(G + 3) / 4, 256, 0, stream>>>(x, offsets, sc, svals, aggb, G,
                                                 GD);
  const int nstripes = (G * 2) / 16;
  const int nblocks = (nstripes + 4 * SPW - 1) / (4 * SPW);
  mfma_fused_kernel<<<nblocks, 256, 0, stream>>>(aggb, Wb, b, gamma, beta,
                                                 (float*)d_out, G);
}

// Round 5
// 227.331 us; speedup vs baseline: 12.2639x; 1.5175x over previous
//
#include <hip/hip_runtime.h>
#include <hip/hip_bf16.h>
#include <math.h>

typedef short bf16x8 __attribute__((ext_vector_type(8)));
typedef float f32x4 __attribute__((ext_vector_type(4)));

#define SPW 4  // stripes (16 rows each) per wave in the MFMA kernel

static __device__ __forceinline__ float bf2f(ushort u) {
  union { unsigned i; float f; } c;
  c.i = ((unsigned)u) << 16;
  return c.f;
}

static __device__ __forceinline__ ushort f2bf(float f) {
  __hip_bfloat16 h = __float2bfloat16(f);
  return *reinterpret_cast<ushort*>(&h);
}

// ---------------------------------------------------------------------------
// fp32 -> bf16 converters (x is large: grid-stride float4)
// ---------------------------------------------------------------------------
__global__ __launch_bounds__(256) void xconv_kernel(const float* __restrict__ x,
                                                    ushort* __restrict__ xb,
                                                    int n4) {
  int i = blockIdx.x * 256 + threadIdx.x;
  const int stride = gridDim.x * 256;
  for (; i < n4; i += stride) {
    float4 v = reinterpret_cast<const float4*>(x)[i];
    ushort4 s;
    s.x = f2bf(v.x);
    s.y = f2bf(v.y);
    s.z = f2bf(v.z);
    s.w = f2bf(v.w);
    reinterpret_cast<ushort4*>(xb)[i] = s;
  }
}

__global__ __launch_bounds__(256) void wconv_kernel(const float* __restrict__ W,
                                                    ushort* __restrict__ Wb,
                                                    int n) {
  int i = blockIdx.x * 256 + threadIdx.x;
  if (i < n) Wb[i] = f2bf(W[i]);
}

// ---------------------------------------------------------------------------
// CSR build: histogram -> 3-phase parallel scan -> scatter-build
// ---------------------------------------------------------------------------
__global__ __launch_bounds__(256) void hist_kernel(const int* __restrict__ rows,
                                                   int* __restrict__ counts,
                                                   int E) {
  int e = blockIdx.x * 256 + threadIdx.x;
  if (e < E) atomicAdd(&counts[rows[e]], 1);
}

// phase 1: per-block (256-elem chunk) sums
__global__ __launch_bounds__(256) void scan1_kernel(
    const int* __restrict__ counts, int* __restrict__ bsums, int G) {
  __shared__ int ws_[4];
  int i = blockIdx.x * 256 + threadIdx.x;
  int v = (i < G) ? counts[i] : 0;
#pragma unroll
  for (int m = 32; m > 0; m >>= 1) v += __shfl_down(v, m);
  if ((threadIdx.x & 63) == 0) ws_[threadIdx.x >> 6] = v;
  __syncthreads();
  if (threadIdx.x == 0)
    bsums[blockIdx.x] = ws_[0] + ws_[1] + ws_[2] + ws_[3];
}

// phase 2: exclusive scan of NB (<=256) block sums; writes offsets[G]=total
__global__ __launch_bounds__(256) void scan2_kernel(int* __restrict__ bsums,
                                                    int* __restrict__ offsets,
                                                    int NB, int G) {
  __shared__ int t[256];
  const int tid = threadIdx.x;
  int v = (tid < NB) ? bsums[tid] : 0;
  t[tid] = v;
  __syncthreads();
  for (int off = 1; off < 256; off <<= 1) {
    int u = (tid >= off) ? t[tid - off] : 0;
    __syncthreads();
    t[tid] += u;
    __syncthreads();
  }
  if (tid < NB) bsums[tid] = t[tid] - v;  // exclusive prefix
  if (tid == 255) offsets[G] = t[255];    // total == E
}

// phase 3: per-chunk exclusive scan + block base -> offsets, cursor
__global__ __launch_bounds__(256) void scan3_kernel(
    const int* __restrict__ counts, const int* __restrict__ bsums,
    int* __restrict__ offsets, int* __restrict__ cursor, int G) {
  __shared__ int t[256];
  const int tid = threadIdx.x;
  const int i = blockIdx.x * 256 + tid;
  int v = (i < G) ? counts[i] : 0;
  t[tid] = v;
  __syncthreads();
  for (int off = 1; off < 256; off <<= 1) {
    int u = (tid >= off) ? t[tid - off] : 0;
    __syncthreads();
    t[tid] += u;
    __syncthreads();
  }
  int ex = t[tid] - v + bsums[blockIdx.x];
  if (i < G) {
    offsets[i] = ex;
    cursor[i] = ex;
  }
}

__global__ __launch_bounds__(256) void build_kernel(
    const int* __restrict__ rows, const int* __restrict__ cols,
    const float* __restrict__ vals, int* __restrict__ cursor,
    int* __restrict__ sc, float* __restrict__ sv, int E) {
  int e = blockIdx.x * 256 + threadIdx.x;
  if (e >= E) return;
  int pos = atomicAdd(&cursor[rows[e]], 1);
  sc[pos] = cols[e];
  sv[pos] = vals[e];
}

// ---------------------------------------------------------------------------
// Gather: one wave per row g; bf16 x, fp32 accumulate, bf16 store.
// Lane -> (l = lane>>5, q = lane&31): elements q*4 .. q*4+3 of the 128-row.
// ---------------------------------------------------------------------------
__global__ __launch_bounds__(256) void gather_kernel(
    const ushort* __restrict__ xb, const int* __restrict__ offsets,
    const int* __restrict__ sc, const float* __restrict__ sv,
    ushort* __restrict__ aggb, int G, int GD) {
  int g = blockIdx.x * 4 + (threadIdx.x >> 6);
  if (g >= G) return;
  const int lane = threadIdx.x & 63;
  const int l = lane >> 5;
  const int q = lane & 31;
  const ushort4* xs = reinterpret_cast<const ushort4*>(xb + (size_t)l * GD);

  int i = offsets[g];
  const int end = offsets[g + 1];
  float4 acc = make_float4(0.f, 0.f, 0.f, 0.f);

  for (; i + 1 < end; i += 2) {
    int c0 = sc[i], c1 = sc[i + 1];
    float v0 = sv[i], v1 = sv[i + 1];
    ushort4 a = xs[(size_t)c0 * 32 + q];
    ushort4 b = xs[(size_t)c1 * 32 + q];
    acc.x += v0 * bf2f(a.x) + v1 * bf2f(b.x);
    acc.y += v0 * bf2f(a.y) + v1 * bf2f(b.y);
    acc.z += v0 * bf2f(a.z) + v1 * bf2f(b.z);
    acc.w += v0 * bf2f(a.w) + v1 * bf2f(b.w);
  }
  if (i < end) {
    int c0 = sc[i];
    float v0 = sv[i];
    ushort4 a = xs[(size_t)c0 * 32 + q];
    acc.x += v0 * bf2f(a.x);
    acc.y += v0 * bf2f(a.y);
    acc.z += v0 * bf2f(a.z);
    acc.w += v0 * bf2f(a.w);
  }
  ushort4 st;
  st.x = f2bf(acc.x);
  st.y = f2bf(acc.y);
  st.z = f2bf(acc.z);
  st.w = f2bf(acc.w);
  *reinterpret_cast<ushort4*>(aggb + (size_t)(g * 2 + l) * 128 + q * 4) = st;
}

// ---------------------------------------------------------------------------
// MFMA GEMM + SiLU + LayerNorm.
// One wave = 16-row stripe x 128 outputs; W entirely in registers (B-frags);
// mfma_f32_16x16x32_bf16; D layout: col(o)=lane&15, row=(lane>>4)*4+reg.
// ---------------------------------------------------------------------------
__global__ __launch_bounds__(256) void mfma_fused_kernel(
    const ushort* __restrict__ ap, const ushort* __restrict__ wp,
    const float* __restrict__ b, const float* __restrict__ gamma,
    const float* __restrict__ beta, float* __restrict__ out, int G) {
  const int lane = threadIdx.x & 63;
  const int wid = blockIdx.x * 4 + (threadIdx.x >> 6);
  const int nstripes = (G * 2) >> 4;

  const int o_lo = lane & 15;
  const int kg = lane >> 4;

  bf16x8 wf[8][4];
#pragma unroll
  for (int on = 0; on < 8; ++on)
#pragma unroll
    for (int kc = 0; kc < 4; ++kc)
      wf[on][kc] = *reinterpret_cast<const bf16x8*>(
          wp + (size_t)(on * 16 + o_lo) * 128 + kc * 32 + kg * 8);

  float bias[8], gam[8], bet[8];
#pragma unroll
  for (int on = 0; on < 8; ++on) {
    bias[on] = b[on * 16 + o_lo];
    gam[on] = gamma[on * 16 + o_lo];
    bet[on] = beta[on * 16 + o_lo];
  }

  for (int i = 0; i < SPW; ++i) {
    const int s = wid * SPW + i;
    if (s >= nstripes) return;
    const int row0 = s << 4;

    bf16x8 af[4];
#pragma unroll
    for (int kc = 0; kc < 4; ++kc)
      af[kc] = *reinterpret_cast<const bf16x8*>(
          ap + (size_t)(row0 + o_lo) * 128 + kc * 32 + kg * 8);

    f32x4 acc[8];
#pragma unroll
    for (int on = 0; on < 8; ++on) acc[on] = (f32x4){0.f, 0.f, 0.f, 0.f};

#pragma unroll
    for (int kc = 0; kc < 4; ++kc)
#pragma unroll
      for (int on = 0; on < 8; ++on)
        acc[on] = __builtin_amdgcn_mfma_f32_16x16x32_bf16(af[kc], wf[on][kc],
                                                          acc[on], 0, 0, 0);

#pragma unroll
    for (int reg = 0; reg < 4; ++reg) {
      const int r = row0 + kg * 4 + reg;
      float svv[8];
      float sum = 0.f, sq = 0.f;
#pragma unroll
      for (int on = 0; on < 8; ++on) {
        float h = acc[on][reg] + bias[on];
        float e = h / (1.f + expf(-h));  // SiLU
        svv[on] = e;
        sum += e;
        sq += e * e;
      }
#pragma unroll
      for (int m = 1; m <= 8; m <<= 1) {
        sum += __shfl_xor(sum, m);
        sq += __shfl_xor(sq, m);
      }
      const float mu = sum * (1.f / 128.f);
      const float var = sq * (1.f / 128.f) - mu * mu;
      const float inv = rsqrtf(var + 1e-5f);
      float* op = out + ((size_t)(r & 1) * G + (r >> 1)) * 128 + o_lo;
#pragma unroll
      for (int on = 0; on < 8; ++on)
        op[on * 16] = (svv[on] - mu) * inv * gam[on] + bet[on];
    }
  }
}

// ---------------------------------------------------------------------------
extern "C" void kernel_launch(void* const* d_in, const int* in_sizes, int n_in,
                              void* d_out, int out_size, void* d_ws,
                              size_t ws_size, hipStream_t stream) {
  const float* x = (const float*)d_in[0];
  const int* rows = (const int*)d_in[1];
  const int* cols = (const int*)d_in[2];
  const float* vals = (const float*)d_in[3];
  const float* W = (const float*)d_in[4];
  const float* b = (const float*)d_in[5];
  const float* gamma = (const float*)d_in[6];
  const float* beta = (const float*)d_in[7];

  const int E = in_sizes[1];
  const int G = in_sizes[0] / 256;  // L=2, D=128
  const int GD = G * 128;
  const int NB = (G + 255) / 256;  // scan blocks (<=256 required)

  // workspace layout
  char* ws = (char*)d_ws;
  ushort* xb = (ushort*)ws;                     // 2G*128 bf16
  ushort* aggb = xb + (size_t)2 * GD;           // 2G*128 bf16
  ushort* Wb = aggb + (size_t)2 * GD;           // 16384 bf16
  int* counts = (int*)(Wb + 16384);             // G
  int* offsets = counts + G;                    // G+1
  int* cursor = offsets + (G + 1);              // G
  int* bsums = cursor + G;                      // NB (<=256)
  int* sc = bsums + 256;                        // E
  float* svals = (float*)(sc + E);              // E

  (void)hipMemsetAsync(counts, 0, (size_t)G * sizeof(int), stream);
  xconv_kernel<<<2048, 256, 0, stream>>>(x, xb, GD / 2);  // 2*GD/4 float4s
  wconv_kernel<<<64, 256, 0, stream>>>(W, Wb, 128 * 128);
  hist_kernel<<<(E + 255) / 256, 256, 0, stream>>>(rows, counts, E);
  scan1_kernel<<<NB, 256, 0, stream>>>(counts, bsums, G);
  scan2_kernel<<<1, 256, 0, stream>>>(bsums, offsets, NB, G);
  scan3_kernel<<<NB, 256, 0, stream>>>(counts, bsums, offsets, cursor, G);
  build_kernel<<<(E + 255) / 256, 256, 0, stream>>>(rows, cols, vals, cursor,
                                                    sc, svals, E);
  gather_kernel<<<(G + 3) / 4, 256, 0, stream>>>(xb, offsets, sc, svals, aggb,
                                                 G, GD);
  const int nstripes = (G * 2) / 16;
  const int nblocks = (nstripes + 4 * SPW - 1) / (4 * SPW);
  mfma_fused_kernel<<<nblocks, 256, 0, stream>>>(aggb, Wb, b, gamma, beta,
                                                 (float*)d_out, G);
}

// Round 6
// 185.846 us; speedup vs baseline: 15.0015x; 1.2232x over previous
//
#include <hip/hip_runtime.h>
#include <hip/hip_bf16.h>
#include <math.h>

typedef short bf16x8 __attribute__((ext_vector_type(8)));
typedef float f32x4 __attribute__((ext_vector_type(4)));

#define SPW 4  // stripes (16 rows each) per wave in the z-GEMM

static __device__ __forceinline__ float bf2f(ushort u) {
  union { unsigned i; float f; } c;
  c.i = ((unsigned)u) << 16;
  return c.f;
}

static __device__ __forceinline__ ushort f2bf(float f) {
  __hip_bfloat16 h = __float2bfloat16(f);
  return *reinterpret_cast<ushort*>(&h);
}

// ---------------------------------------------------------------------------
// W fp32 -> bf16 (16K elements)
// ---------------------------------------------------------------------------
__global__ __launch_bounds__(256) void wconv_kernel(const float* __restrict__ W,
                                                    ushort* __restrict__ Wb,
                                                    int n) {
  int i = blockIdx.x * 256 + threadIdx.x;
  if (i < n) Wb[i] = f2bf(W[i]);
}

// ---------------------------------------------------------------------------
// z-GEMM: z[r][o] = sum_k x[r][k] * W[o][k]   (r = l*G+g, natural x order)
// One wave = 16-row stripe; W in registers; fp32 x converted inline.
// ---------------------------------------------------------------------------
__global__ __launch_bounds__(256) void zgemm_kernel(
    const float* __restrict__ x, const ushort* __restrict__ wp,
    ushort* __restrict__ zb, int nstripes) {
  const int lane = threadIdx.x & 63;
  const int wid = blockIdx.x * 4 + (threadIdx.x >> 6);

  const int o_lo = lane & 15;
  const int kg = lane >> 4;

  bf16x8 wf[8][4];
#pragma unroll
  for (int on = 0; on < 8; ++on)
#pragma unroll
    for (int kc = 0; kc < 4; ++kc)
      wf[on][kc] = *reinterpret_cast<const bf16x8*>(
          wp + (size_t)(on * 16 + o_lo) * 128 + kc * 32 + kg * 8);

  for (int i = 0; i < SPW; ++i) {
    const int s = wid * SPW + i;
    if (s >= nstripes) return;
    const int row0 = s << 4;

    bf16x8 af[4];
#pragma unroll
    for (int kc = 0; kc < 4; ++kc) {
      const float* src = x + (size_t)(row0 + o_lo) * 128 + kc * 32 + kg * 8;
      float4 v0 = *reinterpret_cast<const float4*>(src);
      float4 v1 = *reinterpret_cast<const float4*>(src + 4);
      bf16x8 t;
      t[0] = (short)f2bf(v0.x); t[1] = (short)f2bf(v0.y);
      t[2] = (short)f2bf(v0.z); t[3] = (short)f2bf(v0.w);
      t[4] = (short)f2bf(v1.x); t[5] = (short)f2bf(v1.y);
      t[6] = (short)f2bf(v1.z); t[7] = (short)f2bf(v1.w);
      af[kc] = t;
    }

    f32x4 acc[8];
#pragma unroll
    for (int on = 0; on < 8; ++on) acc[on] = (f32x4){0.f, 0.f, 0.f, 0.f};

#pragma unroll
    for (int kc = 0; kc < 4; ++kc)
#pragma unroll
      for (int on = 0; on < 8; ++on)
        acc[on] = __builtin_amdgcn_mfma_f32_16x16x32_bf16(af[kc], wf[on][kc],
                                                          acc[on], 0, 0, 0);

    // D layout: col = o_lo, row = kg*4 + reg
#pragma unroll
    for (int reg = 0; reg < 4; ++reg) {
      ushort* zr = zb + (size_t)(row0 + kg * 4 + reg) * 128 + o_lo;
#pragma unroll
      for (int on = 0; on < 8; ++on) zr[on * 16] = f2bf(acc[on][reg]);
    }
  }
}

// ---------------------------------------------------------------------------
// CSR build: histogram -> 3-phase parallel scan -> scatter-build (int2 pairs)
// ---------------------------------------------------------------------------
__global__ __launch_bounds__(256) void hist_kernel(const int* __restrict__ rows,
                                                   int* __restrict__ counts,
                                                   int E) {
  int e = blockIdx.x * 256 + threadIdx.x;
  if (e < E) atomicAdd(&counts[rows[e]], 1);
}

__global__ __launch_bounds__(256) void scan1_kernel(
    const int* __restrict__ counts, int* __restrict__ bsums, int G) {
  __shared__ int ws_[4];
  int i = blockIdx.x * 256 + threadIdx.x;
  int v = (i < G) ? counts[i] : 0;
#pragma unroll
  for (int m = 32; m > 0; m >>= 1) v += __shfl_down(v, m);
  if ((threadIdx.x & 63) == 0) ws_[threadIdx.x >> 6] = v;
  __syncthreads();
  if (threadIdx.x == 0)
    bsums[blockIdx.x] = ws_[0] + ws_[1] + ws_[2] + ws_[3];
}

__global__ __launch_bounds__(256) void scan2_kernel(int* __restrict__ bsums,
                                                    int* __restrict__ offsets,
                                                    int NB, int G) {
  __shared__ int t[256];
  const int tid = threadIdx.x;
  int v = (tid < NB) ? bsums[tid] : 0;
  t[tid] = v;
  __syncthreads();
  for (int off = 1; off < 256; off <<= 1) {
    int u = (tid >= off) ? t[tid - off] : 0;
    __syncthreads();
    t[tid] += u;
    __syncthreads();
  }
  if (tid < NB) bsums[tid] = t[tid] - v;
  if (tid == 255) offsets[G] = t[255];
}

__global__ __launch_bounds__(256) void scan3_kernel(
    const int* __restrict__ counts, const int* __restrict__ bsums,
    int* __restrict__ offsets, int* __restrict__ cursor, int G) {
  __shared__ int t[256];
  const int tid = threadIdx.x;
  const int i = blockIdx.x * 256 + tid;
  int v = (i < G) ? counts[i] : 0;
  t[tid] = v;
  __syncthreads();
  for (int off = 1; off < 256; off <<= 1) {
    int u = (tid >= off) ? t[tid - off] : 0;
    __syncthreads();
    t[tid] += u;
    __syncthreads();
  }
  int ex = t[tid] - v + bsums[blockIdx.x];
  if (i < G) {
    offsets[i] = ex;
    cursor[i] = ex;
  }
}

__global__ __launch_bounds__(256) void build_kernel(
    const int* __restrict__ rows, const int* __restrict__ cols,
    const float* __restrict__ vals, int* __restrict__ cursor,
    int2* __restrict__ ev, int E) {
  int e = blockIdx.x * 256 + threadIdx.x;
  if (e >= E) return;
  int pos = atomicAdd(&cursor[rows[e]], 1);
  ev[pos] = make_int2(cols[e], __float_as_int(vals[e]));
}

// ---------------------------------------------------------------------------
// Fused gather + bias + SiLU + LayerNorm.
// One wave per g.  Lane -> (l = lane>>5, q = lane&31): 4 elems of h[l][g][:].
// h[l][g][d] = sum_e v_e * z[l][c_e][d] + b[d];  LN over 32-lane half-wave.
// ---------------------------------------------------------------------------
__global__ __launch_bounds__(256) void gather_fused_kernel(
    const ushort* __restrict__ zb, const int* __restrict__ offsets,
    const int2* __restrict__ ev, const float* __restrict__ b,
    const float* __restrict__ gamma, const float* __restrict__ beta,
    float* __restrict__ out, int G, int GD) {
  int g = blockIdx.x * 4 + (threadIdx.x >> 6);
  if (g >= G) return;
  const int lane = threadIdx.x & 63;
  const int l = lane >> 5;
  const int q = lane & 31;
  const ushort4* zs = reinterpret_cast<const ushort4*>(zb + (size_t)l * GD);

  int i = offsets[g];
  const int end = offsets[g + 1];
  float4 acc = make_float4(0.f, 0.f, 0.f, 0.f);

  for (; i + 3 < end; i += 4) {
    int2 e0 = ev[i], e1 = ev[i + 1], e2 = ev[i + 2], e3 = ev[i + 3];
    ushort4 a0 = zs[(size_t)e0.x * 32 + q];
    ushort4 a1 = zs[(size_t)e1.x * 32 + q];
    ushort4 a2 = zs[(size_t)e2.x * 32 + q];
    ushort4 a3 = zs[(size_t)e3.x * 32 + q];
    float v0 = __int_as_float(e0.y), v1 = __int_as_float(e1.y);
    float v2 = __int_as_float(e2.y), v3 = __int_as_float(e3.y);
    acc.x += v0 * bf2f(a0.x) + v1 * bf2f(a1.x) + v2 * bf2f(a2.x) + v3 * bf2f(a3.x);
    acc.y += v0 * bf2f(a0.y) + v1 * bf2f(a1.y) + v2 * bf2f(a2.y) + v3 * bf2f(a3.y);
    acc.z += v0 * bf2f(a0.z) + v1 * bf2f(a1.z) + v2 * bf2f(a2.z) + v3 * bf2f(a3.z);
    acc.w += v0 * bf2f(a0.w) + v1 * bf2f(a1.w) + v2 * bf2f(a2.w) + v3 * bf2f(a3.w);
  }
  for (; i < end; ++i) {
    int2 e0 = ev[i];
    float v0 = __int_as_float(e0.y);
    ushort4 a0 = zs[(size_t)e0.x * 32 + q];
    acc.x += v0 * bf2f(a0.x);
    acc.y += v0 * bf2f(a0.y);
    acc.z += v0 * bf2f(a0.z);
    acc.w += v0 * bf2f(a0.w);
  }

  // epilogue: bias + SiLU + LayerNorm (over this 32-lane group's 128 values)
  const int d0 = q * 4;
  const float4 bb = *reinterpret_cast<const float4*>(b + d0);
  float4 s;
  {
    float h0 = acc.x + bb.x, h1 = acc.y + bb.y;
    float h2 = acc.z + bb.z, h3 = acc.w + bb.w;
    s.x = h0 / (1.f + expf(-h0));
    s.y = h1 / (1.f + expf(-h1));
    s.z = h2 / (1.f + expf(-h2));
    s.w = h3 / (1.f + expf(-h3));
  }
  float sum = s.x + s.y + s.z + s.w;
  float sq = s.x * s.x + s.y * s.y + s.z * s.z + s.w * s.w;
#pragma unroll
  for (int m = 1; m <= 16; m <<= 1) {  // stays within the 32-lane half-wave
    sum += __shfl_xor(sum, m);
    sq += __shfl_xor(sq, m);
  }
  const float mu = sum * (1.f / 128.f);
  const float var = sq * (1.f / 128.f) - mu * mu;
  const float inv = rsqrtf(var + 1e-5f);
  const float4 gm = *reinterpret_cast<const float4*>(gamma + d0);
  const float4 bt = *reinterpret_cast<const float4*>(beta + d0);
  float4 o;
  o.x = (s.x - mu) * inv * gm.x + bt.x;
  o.y = (s.y - mu) * inv * gm.y + bt.y;
  o.z = (s.z - mu) * inv * gm.z + bt.z;
  o.w = (s.w - mu) * inv * gm.w + bt.w;
  *reinterpret_cast<float4*>(out + (size_t)l * GD + (size_t)g * 128 + d0) = o;
}

// ---------------------------------------------------------------------------
extern "C" void kernel_launch(void* const* d_in, const int* in_sizes, int n_in,
                              void* d_out, int out_size, void* d_ws,
                              size_t ws_size, hipStream_t stream) {
  const float* x = (const float*)d_in[0];
  const int* rows = (const int*)d_in[1];
  const int* cols = (const int*)d_in[2];
  const float* vals = (const float*)d_in[3];
  const float* W = (const float*)d_in[4];
  const float* b = (const float*)d_in[5];
  const float* gamma = (const float*)d_in[6];
  const float* beta = (const float*)d_in[7];

  const int E = in_sizes[1];
  const int G = in_sizes[0] / 256;  // L=2, D=128
  const int GD = G * 128;
  const int NB = (G + 255) / 256;  // scan blocks (<=256 required)

  // workspace layout
  char* ws = (char*)d_ws;
  ushort* zb = (ushort*)ws;                 // 2G*128 bf16
  ushort* Wb = zb + (size_t)2 * GD;         // 16384 bf16
  int* counts = (int*)(Wb + 16384);         // G
  int* offsets = counts + G;                // G+1
  int* cursor = offsets + (G + 1);          // G
  int* bsums = cursor + G;                  // 256
  int2* ev = (int2*)(bsums + 256);          // E int2

  (void)hipMemsetAsync(counts, 0, (size_t)G * sizeof(int), stream);
  wconv_kernel<<<64, 256, 0, stream>>>(W, Wb, 128 * 128);
  hist_kernel<<<(E + 255) / 256, 256, 0, stream>>>(rows, counts, E);
  scan1_kernel<<<NB, 256, 0, stream>>>(counts, bsums, G);
  scan2_kernel<<<1, 256, 0, stream>>>(bsums, offsets, NB, G);
  scan3_kernel<<<NB, 256, 0, stream>>>(counts, bsums, offsets, cursor, G);
  build_kernel<<<(E + 255) / 256, 256, 0, stream>>>(rows, cols, vals, cursor,
                                                    ev, E);
  const int nstripes = (G * 2) / 16;
  zgemm_kernel<<<(nstripes + 4 * SPW - 1) / (4 * SPW), 256, 0, stream>>>(
      x, Wb, zb, nstripes);
  gather_fused_kernel<<<(G + 3) / 4, 256, 0, stream>>>(zb, offsets, ev, b,
                                                       gamma, beta,
                                                       (float*)d_out, G, GD);
}